// Round 1
// baseline (190.317 us; speedup 1.0000x reference)
//
#include <hip/hip_runtime.h>
#include <math.h>

#define LQ 6400

// ---------------------------------------------------------------------------
// Kernel 1: per-level feature projection
// P_l[(y*W+x)*128 + co] = sum_ci Wk_l[co*C + ci] * feat_l[ci*HW + y*W + x]
// (bias bk is added later, after bilinear interpolation, to preserve
//  zero-padding semantics of grid_sample)
// Block: 256 thr; tile = 64 output channels (half) x 64 spatial positions.
// ---------------------------------------------------------------------------
__global__ __launch_bounds__(256) void proj_kernel(
    const float* __restrict__ feat0, const float* __restrict__ feat1,
    const float* __restrict__ feat2,
    const float* __restrict__ Wk0, const float* __restrict__ Wk1,
    const float* __restrict__ Wk2,
    float* __restrict__ P0, float* __restrict__ P1, float* __restrict__ P2)
{
    __shared__ float wk_sh[64 * 128];               // 32 KB, XOR-swizzled rows
    __shared__ __align__(16) float f_sh[128 * 64];  // 32 KB
    int b = blockIdx.x;
    const float* feat; const float* Wk; float* P;
    int C, HW, local;
    if (b < 512)      { feat = feat0; Wk = Wk0; P = P0; C = 128; HW = 16384; local = b; }
    else if (b < 640) { feat = feat1; Wk = Wk1; P = P1; C = 128; HW = 4096;  local = b - 512; }
    else              { feat = feat2; Wk = Wk2; P = P2; C = 64;  HW = 1024;  local = b - 640; }
    int pblk = local >> 1;
    int half = local & 1;
    int cbase = half * 64;
    int p0 = pblk * 64;
    int tid = threadIdx.x;
    int cmask = C - 1;
    int csh = (C == 128) ? 7 : 6;

    // stage Wk half (64 rows x C), column XOR-swizzled by (row & 31):
    // read of (row=c0+32k, ci) lands in bank (ci^c0)&31 -> conflict-free.
    for (int idx = tid; idx < 64 * C; idx += 256) {
        int rl = idx >> csh;
        int ci = idx & cmask;
        wk_sh[rl * C + (ci ^ (rl & 31))] = Wk[(cbase + rl) * C + ci];
    }
    // stage feat tile (C x 64 positions), coalesced
    for (int idx = tid; idx < C * 64; idx += 256) {
        int ci = idx >> 6;
        int pp = idx & 63;
        f_sh[ci * 64 + pp] = feat[ci * HW + p0 + pp];
    }
    __syncthreads();

    int c0 = tid & 31;   // output-channel lane
    int pg = tid >> 5;   // 0..7, 8 positions each
    float acc[2][8];
    #pragma unroll
    for (int k = 0; k < 2; ++k)
        #pragma unroll
        for (int j = 0; j < 8; ++j) acc[k][j] = 0.f;

    #pragma unroll 2
    for (int ci = 0; ci < C; ++ci) {
        float a0 = wk_sh[c0 * C + (ci ^ c0)];
        float a1 = wk_sh[(c0 + 32) * C + (ci ^ c0)];
        const float4 bv0 = *reinterpret_cast<const float4*>(&f_sh[ci * 64 + pg * 8]);
        const float4 bv1 = *reinterpret_cast<const float4*>(&f_sh[ci * 64 + pg * 8 + 4]);
        float bb[8] = {bv0.x, bv0.y, bv0.z, bv0.w, bv1.x, bv1.y, bv1.z, bv1.w};
        #pragma unroll
        for (int j = 0; j < 8; ++j) {
            acc[0][j] = fmaf(a0, bb[j], acc[0][j]);
            acc[1][j] = fmaf(a1, bb[j], acc[1][j]);
        }
    }
    #pragma unroll
    for (int k = 0; k < 2; ++k)
        #pragma unroll
        for (int j = 0; j < 8; ++j)
            P[(p0 + pg * 8 + j) * 128 + cbase + c0 + 32 * k] = acc[k][j];
}

// ---------------------------------------------------------------------------
// Kernel 2: sampling offsets  off[q][r] = W_off[r] . query[q] + b_off[r]
// Block tile: 96 rows (half) x 32 queries.
// ---------------------------------------------------------------------------
__global__ __launch_bounds__(256) void off_kernel(
    const float* __restrict__ query, const float* __restrict__ W_off,
    const float* __restrict__ b_off, float* __restrict__ offv)
{
    __shared__ float w_sh[96 * 128];  // 48 KB swizzled
    __shared__ float q_sh[32 * 128];  // 16 KB
    int b = blockIdx.x;
    int qblk = b >> 1;
    int half = b & 1;
    int rbase = half * 96;
    int q0 = qblk * 32;
    int tid = threadIdx.x;

    for (int idx = tid; idx < 96 * 128; idx += 256) {
        int rl = idx >> 7;
        int ci = idx & 127;
        w_sh[rl * 128 + (ci ^ (rl & 31))] = W_off[(rbase + rl) * 128 + ci];
    }
    for (int idx = tid; idx < 32 * 128; idx += 256) {
        int qq = idx >> 7;
        int ci = idx & 127;
        q_sh[qq * 128 + ci] = query[(q0 + qq) * 128 + ci];
    }
    __syncthreads();

    int c0 = tid & 31;
    int qg = tid >> 5;  // 8 groups x 4 queries
    float acc[3][4];
    #pragma unroll
    for (int k = 0; k < 3; ++k)
        #pragma unroll
        for (int j = 0; j < 4; ++j) acc[k][j] = 0.f;

    #pragma unroll 4
    for (int ci = 0; ci < 128; ++ci) {
        float a0 = w_sh[c0 * 128 + (ci ^ c0)];
        float a1 = w_sh[(c0 + 32) * 128 + (ci ^ c0)];
        float a2 = w_sh[(c0 + 64) * 128 + (ci ^ c0)];
        float b0 = q_sh[(qg * 4 + 0) * 128 + ci];
        float b1 = q_sh[(qg * 4 + 1) * 128 + ci];
        float b2 = q_sh[(qg * 4 + 2) * 128 + ci];
        float b3 = q_sh[(qg * 4 + 3) * 128 + ci];
        acc[0][0] = fmaf(a0, b0, acc[0][0]); acc[0][1] = fmaf(a0, b1, acc[0][1]);
        acc[0][2] = fmaf(a0, b2, acc[0][2]); acc[0][3] = fmaf(a0, b3, acc[0][3]);
        acc[1][0] = fmaf(a1, b0, acc[1][0]); acc[1][1] = fmaf(a1, b1, acc[1][1]);
        acc[1][2] = fmaf(a1, b2, acc[1][2]); acc[1][3] = fmaf(a1, b3, acc[1][3]);
        acc[2][0] = fmaf(a2, b0, acc[2][0]); acc[2][1] = fmaf(a2, b1, acc[2][1]);
        acc[2][2] = fmaf(a2, b2, acc[2][2]); acc[2][3] = fmaf(a2, b3, acc[2][3]);
    }
    #pragma unroll
    for (int k = 0; k < 3; ++k) {
        int r = rbase + c0 + 32 * k;
        float bias = b_off[r];
        #pragma unroll
        for (int j = 0; j < 4; ++j)
            offv[(q0 + qg * 4 + j) * 192 + r] = acc[k][j] + bias;
    }
}

// ---------------------------------------------------------------------------
// Kernel 3: per-query sampling + attention.
// One block (256 thr) per query. 16 lanes serve one (head,level,point) sample.
// ---------------------------------------------------------------------------
__global__ __launch_bounds__(256) void attn_kernel(
    const float* __restrict__ query, const float* __restrict__ ref,
    const float* __restrict__ offv,
    const float* __restrict__ P0, const float* __restrict__ P1,
    const float* __restrict__ P2,
    const float* __restrict__ bk0, const float* __restrict__ bk1,
    const float* __restrict__ bk2,
    float* __restrict__ hout)
{
    __shared__ float q_sh[128];
    __shared__ float logit_sh[8][12];
    __shared__ float k_sh[8][12][17];  // padded
    int q = blockIdx.x;
    int tid = threadIdx.x;
    if (tid < 128) q_sh[tid] = query[q * 128 + tid];
    __syncthreads();

    int grp = tid >> 4;  // 0..15 sample groups
    int d = tid & 15;    // head-dim lane
    #pragma unroll
    for (int it = 0; it < 6; ++it) {
        int s = it * 16 + grp;        // 0..95 ; s == (h*3+l)*4+p
        int h = s / 12;
        int lp = s - h * 12;
        int l = lp >> 2;
        const float* P; const float* bk; int W, H;
        if (l == 0)      { P = P0; bk = bk0; W = 128; H = 128; }
        else if (l == 1) { P = P1; bk = bk1; W = 64;  H = 64;  }
        else             { P = P2; bk = bk2; W = 32;  H = 32;  }
        float ox = offv[q * 192 + 2 * s];
        float oy = offv[q * 192 + 2 * s + 1];
        float rx = ref[(q * 3 + l) * 2 + 0];
        float ry = ref[(q * 3 + l) * 2 + 1];
        // 1/W, 1/H are exact powers of two -> matches reference's off/norm
        float lx = rx + ox * (1.0f / (float)W);
        float ly = ry + oy * (1.0f / (float)H);
        float x = lx * (float)W - 0.5f;
        float y = ly * (float)H - 0.5f;
        float x0f = floorf(x), y0f = floorf(y);
        float wx = x - x0f, wy = y - y0f;
        int x0 = (int)x0f, y0 = (int)y0f;
        int x1 = x0 + 1, y1 = y0 + 1;
        float w00 = (1.f - wx) * (1.f - wy);
        float w10 = wx * (1.f - wy);
        float w01 = (1.f - wx) * wy;
        float w11 = wx * wy;
        int co = h * 16 + d;
        bool vx0 = (x0 >= 0) & (x0 < W);
        bool vx1 = (x1 >= 0) & (x1 < W);
        bool vy0 = (y0 >= 0) & (y0 < H);
        bool vy1 = (y1 >= 0) & (y1 < H);
        float acc = 0.f;
        if (vx0 & vy0) acc = fmaf(w00, P[(y0 * W + x0) * 128 + co], acc);
        if (vx1 & vy0) acc = fmaf(w10, P[(y0 * W + x1) * 128 + co], acc);
        if (vx0 & vy1) acc = fmaf(w01, P[(y1 * W + x0) * 128 + co], acc);
        if (vx1 & vy1) acc = fmaf(w11, P[(y1 * W + x1) * 128 + co], acc);
        float kv = acc + bk[co];
        float prod = q_sh[co] * kv;
        prod += __shfl_xor(prod, 1);
        prod += __shfl_xor(prod, 2);
        prod += __shfl_xor(prod, 4);
        prod += __shfl_xor(prod, 8);
        k_sh[h][lp][d] = kv;
        if (d == 0) logit_sh[h][lp] = prod;
    }
    __syncthreads();

    if (tid < 128) {
        int h = tid >> 4, dd = tid & 15;
        float m = -1e30f;
        #pragma unroll
        for (int j = 0; j < 12; ++j) m = fmaxf(m, logit_sh[h][j]);
        float ssum = 0.f, o = 0.f;
        #pragma unroll
        for (int j = 0; j < 12; ++j) {
            float e = __expf(0.25f * (logit_sh[h][j] - m));
            ssum += e;
            o = fmaf(e, k_sh[h][j][dd], o);
        }
        hout[q * 128 + tid] = o / ssum;
    }
}

// ---------------------------------------------------------------------------
// Kernel 4: output projection  out[q][co] = W_out[co] . hout[q] + b_out[co]
// Block tile: 64 rows (half) x 32 queries.
// ---------------------------------------------------------------------------
__global__ __launch_bounds__(256) void outp_kernel(
    const float* __restrict__ hin, const float* __restrict__ W_out,
    const float* __restrict__ b_out, float* __restrict__ out)
{
    __shared__ float w_sh[64 * 128];  // 32 KB swizzled
    __shared__ float q_sh[32 * 128];  // 16 KB
    int b = blockIdx.x;
    int qblk = b >> 1;
    int half = b & 1;
    int rbase = half * 64;
    int q0 = qblk * 32;
    int tid = threadIdx.x;

    for (int idx = tid; idx < 64 * 128; idx += 256) {
        int rl = idx >> 7;
        int ci = idx & 127;
        w_sh[rl * 128 + (ci ^ (rl & 31))] = W_out[(rbase + rl) * 128 + ci];
    }
    for (int idx = tid; idx < 32 * 128; idx += 256) {
        int qq = idx >> 7;
        int ci = idx & 127;
        q_sh[qq * 128 + ci] = hin[(q0 + qq) * 128 + ci];
    }
    __syncthreads();

    int c0 = tid & 31;
    int qg = tid >> 5;
    float acc[2][4];
    #pragma unroll
    for (int k = 0; k < 2; ++k)
        #pragma unroll
        for (int j = 0; j < 4; ++j) acc[k][j] = 0.f;

    #pragma unroll 4
    for (int ci = 0; ci < 128; ++ci) {
        float a0 = w_sh[c0 * 128 + (ci ^ c0)];
        float a1 = w_sh[(c0 + 32) * 128 + (ci ^ c0)];
        float b0 = q_sh[(qg * 4 + 0) * 128 + ci];
        float b1 = q_sh[(qg * 4 + 1) * 128 + ci];
        float b2 = q_sh[(qg * 4 + 2) * 128 + ci];
        float b3 = q_sh[(qg * 4 + 3) * 128 + ci];
        acc[0][0] = fmaf(a0, b0, acc[0][0]); acc[0][1] = fmaf(a0, b1, acc[0][1]);
        acc[0][2] = fmaf(a0, b2, acc[0][2]); acc[0][3] = fmaf(a0, b3, acc[0][3]);
        acc[1][0] = fmaf(a1, b0, acc[1][0]); acc[1][1] = fmaf(a1, b1, acc[1][1]);
        acc[1][2] = fmaf(a1, b2, acc[1][2]); acc[1][3] = fmaf(a1, b3, acc[1][3]);
    }
    #pragma unroll
    for (int k = 0; k < 2; ++k) {
        int r = rbase + c0 + 32 * k;
        float bias = b_out[r];
        #pragma unroll
        for (int j = 0; j < 4; ++j)
            out[(q0 + qg * 4 + j) * 128 + r] = acc[k][j] + bias;
    }
}

// ---------------------------------------------------------------------------
extern "C" void kernel_launch(void* const* d_in, const int* in_sizes, int n_in,
                              void* d_out, int out_size, void* d_ws, size_t ws_size,
                              hipStream_t stream) {
    const float* query = (const float*)d_in[0];
    const float* ref   = (const float*)d_in[1];
    const float* feat0 = (const float*)d_in[2];
    const float* feat1 = (const float*)d_in[3];
    const float* feat2 = (const float*)d_in[4];
    // d_in[5] = input_spatial_shapes (constants, hardcoded)
    const float* W_off = (const float*)d_in[6];
    const float* b_off = (const float*)d_in[7];
    const float* Wk0   = (const float*)d_in[8];
    const float* bk0   = (const float*)d_in[9];
    const float* Wk1   = (const float*)d_in[10];
    const float* bk1   = (const float*)d_in[11];
    const float* Wk2   = (const float*)d_in[12];
    const float* bk2   = (const float*)d_in[13];
    const float* W_out = (const float*)d_in[14];
    const float* b_out = (const float*)d_in[15];
    float* out = (float*)d_out;

    float* P0   = (float*)d_ws;                 // 16384*128
    float* P1   = P0 + 16384 * 128;             // 4096*128
    float* P2   = P1 + 4096 * 128;              // 1024*128
    float* offv = P2 + 1024 * 128;              // 6400*192
    float* hout = offv + 6400 * 192;            // 6400*128

    hipLaunchKernelGGL(proj_kernel, dim3(672), dim3(256), 0, stream,
                       feat0, feat1, feat2, Wk0, Wk1, Wk2, P0, P1, P2);
    hipLaunchKernelGGL(off_kernel, dim3(400), dim3(256), 0, stream,
                       query, W_off, b_off, offv);
    hipLaunchKernelGGL(attn_kernel, dim3(6400), dim3(256), 0, stream,
                       query, ref, offv, P0, P1, P2, bk0, bk1, bk2, hout);
    hipLaunchKernelGGL(outp_kernel, dim3(400), dim3(256), 0, stream,
                       hout, W_out, b_out, out);
}

// Round 2
// 161.407 us; speedup vs baseline: 1.1791x; 1.1791x over previous
//
#include <hip/hip_runtime.h>
#include <hip/hip_bf16.h>
#include <math.h>

#define LQ 6400

// ---------------------------------------------------------------------------
// Kernel 1: per-level feature projection -> bf16 P maps.
// P[(y*W+x)*128 + co] = sum_ci Wk[co*C + ci] * feat[ci*HW + y*W+x]
// Tile: 64 out-channels (half) x 64 positions, K=C. float4 LDS reads,
// XOR-swizzled weight tile (conflict-free b128), per-thread 2x8 register tile.
// ---------------------------------------------------------------------------
template<int C>
__global__ __launch_bounds__(256) void proj2_kernel(
    const float* __restrict__ fA, const float* __restrict__ fB,
    const float* __restrict__ WA, const float* __restrict__ WB,
    __hip_bfloat16* __restrict__ PA, __hip_bfloat16* __restrict__ PB,
    int splitB, int HWA, int HWB)
{
    constexpr int CI4 = C / 4;
    __shared__ float wk_sh[64 * C];   // swizzled in float4 granules
    __shared__ float f_sh[C * 64];
    int b = blockIdx.x;
    const float* feat; const float* Wk; __hip_bfloat16* P; int HW, local;
    if (b < splitB) { feat = fA; Wk = WA; P = PA; HW = HWA; local = b; }
    else            { feat = fB; Wk = WB; P = PB; HW = HWB; local = b - splitB; }
    int pblk = local >> 1;
    int half = local & 1;
    int cbase = half * 64;
    int p0 = pblk * 64;
    int tid = threadIdx.x;

    // stage Wk half (64 rows x C), float4-granule XOR swizzle by (row & (CI4-1))
    for (int idx = tid; idx < 64 * CI4; idx += 256) {
        int rl = idx / CI4;
        int ci4 = idx % CI4;
        float4 v = *reinterpret_cast<const float4*>(&Wk[(cbase + rl) * C + ci4 * 4]);
        *reinterpret_cast<float4*>(&wk_sh[rl * C + ((ci4 ^ (rl & (CI4 - 1))) << 2)]) = v;
    }
    // stage feat tile [C][64], coalesced float4
    for (int idx = tid; idx < C * 16; idx += 256) {
        int ci = idx >> 4;
        int pp4 = idx & 15;
        float4 v = *reinterpret_cast<const float4*>(&feat[ci * HW + p0 + pp4 * 4]);
        *reinterpret_cast<float4*>(&f_sh[ci * 64 + pp4 * 4]) = v;
    }
    __syncthreads();

    int c0 = tid & 31;   // output-channel lane (rows c0, c0+32)
    int pg = tid >> 5;   // 8 groups x 8 positions
    const int sw = c0 & (CI4 - 1);
    float acc[2][8];
    #pragma unroll
    for (int k = 0; k < 2; ++k)
        #pragma unroll
        for (int j = 0; j < 8; ++j) acc[k][j] = 0.f;

    #pragma unroll 4
    for (int ci4 = 0; ci4 < CI4; ++ci4) {
        float4 A0 = *reinterpret_cast<const float4*>(&wk_sh[c0 * C + ((ci4 ^ sw) << 2)]);
        float4 A1 = *reinterpret_cast<const float4*>(&wk_sh[(c0 + 32) * C + ((ci4 ^ sw) << 2)]);
        float a0v[4] = {A0.x, A0.y, A0.z, A0.w};
        float a1v[4] = {A1.x, A1.y, A1.z, A1.w};
        #pragma unroll
        for (int jj = 0; jj < 4; ++jj) {
            int ci = ci4 * 4 + jj;
            float4 Blo = *reinterpret_cast<const float4*>(&f_sh[ci * 64 + pg * 8]);
            float4 Bhi = *reinterpret_cast<const float4*>(&f_sh[ci * 64 + pg * 8 + 4]);
            float bv[8] = {Blo.x, Blo.y, Blo.z, Blo.w, Bhi.x, Bhi.y, Bhi.z, Bhi.w};
            #pragma unroll
            for (int j = 0; j < 8; ++j) {
                acc[0][j] = fmaf(a0v[jj], bv[j], acc[0][j]);
                acc[1][j] = fmaf(a1v[jj], bv[j], acc[1][j]);
            }
        }
    }
    #pragma unroll
    for (int k = 0; k < 2; ++k) {
        int co = cbase + c0 + 32 * k;
        #pragma unroll
        for (int j = 0; j < 8; ++j)
            P[(size_t)(p0 + pg * 8 + j) * 128 + co] = __float2bfloat16(acc[k][j]);
    }
}

// ---------------------------------------------------------------------------
// Kernel 2: sampling offsets. Tile 96 rows (half) x 32 queries, K=128.
// ---------------------------------------------------------------------------
__global__ __launch_bounds__(256) void off2_kernel(
    const float* __restrict__ query, const float* __restrict__ W_off,
    const float* __restrict__ b_off, float* __restrict__ offv)
{
    __shared__ float w_sh[96 * 128];  // 48 KB swizzled (float4 granules)
    __shared__ float q_sh[32 * 128];  // 16 KB
    int b = blockIdx.x;
    int qblk = b >> 1;
    int half = b & 1;
    int rbase = half * 96;
    int q0 = qblk * 32;
    int tid = threadIdx.x;

    for (int idx = tid; idx < 96 * 32; idx += 256) {
        int rl = idx >> 5;
        int ci4 = idx & 31;
        float4 v = *reinterpret_cast<const float4*>(&W_off[(rbase + rl) * 128 + ci4 * 4]);
        *reinterpret_cast<float4*>(&w_sh[rl * 128 + ((ci4 ^ (rl & 31)) << 2)]) = v;
    }
    for (int idx = tid; idx < 32 * 32; idx += 256) {
        int qq = idx >> 5;
        int ci4 = idx & 31;
        *reinterpret_cast<float4*>(&q_sh[qq * 128 + ci4 * 4]) =
            *reinterpret_cast<const float4*>(&query[(q0 + qq) * 128 + ci4 * 4]);
    }
    __syncthreads();

    int c0 = tid & 31;   // rows c0, c0+32, c0+64 (all &31 == c0)
    int qg = tid >> 5;   // 8 groups x 4 queries
    float acc[3][4];
    #pragma unroll
    for (int k = 0; k < 3; ++k)
        #pragma unroll
        for (int j = 0; j < 4; ++j) acc[k][j] = 0.f;

    #pragma unroll 4
    for (int ci4 = 0; ci4 < 32; ++ci4) {
        float4 A[3];
        #pragma unroll
        for (int k = 0; k < 3; ++k)
            A[k] = *reinterpret_cast<const float4*>(&w_sh[(c0 + 32 * k) * 128 + ((ci4 ^ c0) << 2)]);
        #pragma unroll
        for (int j = 0; j < 4; ++j) {
            float4 B = *reinterpret_cast<const float4*>(&q_sh[(qg * 4 + j) * 128 + ci4 * 4]);
            #pragma unroll
            for (int k = 0; k < 3; ++k) {
                acc[k][j] = fmaf(A[k].x, B.x, acc[k][j]);
                acc[k][j] = fmaf(A[k].y, B.y, acc[k][j]);
                acc[k][j] = fmaf(A[k].z, B.z, acc[k][j]);
                acc[k][j] = fmaf(A[k].w, B.w, acc[k][j]);
            }
        }
    }
    #pragma unroll
    for (int k = 0; k < 3; ++k) {
        int r = rbase + c0 + 32 * k;
        float bias = b_off[r];
        #pragma unroll
        for (int j = 0; j < 4; ++j)
            offv[(q0 + qg * 4 + j) * 192 + r] = acc[k][j] + bias;
    }
}

// ---------------------------------------------------------------------------
// Kernel 3: per-query sampling + attention (P maps in bf16).
// One block (256 thr) per query; 16 lanes per (head,level,point) sample.
// Unconditional clamped corner loads; validity folded into bilinear weights.
// ---------------------------------------------------------------------------
__global__ __launch_bounds__(256) void attn2_kernel(
    const float* __restrict__ query, const float* __restrict__ ref,
    const float* __restrict__ offv,
    const __hip_bfloat16* __restrict__ P0, const __hip_bfloat16* __restrict__ P1,
    const __hip_bfloat16* __restrict__ P2,
    const float* __restrict__ bk0, const float* __restrict__ bk1,
    const float* __restrict__ bk2,
    float* __restrict__ hout)
{
    __shared__ float q_sh[128];
    __shared__ float off_sh[192];
    __shared__ float ref_sh[6];
    __shared__ float bias_sh[3][128];
    __shared__ float logit_sh[8][12];
    __shared__ float k_sh[8][12][17];
    int q = blockIdx.x;
    int tid = threadIdx.x;
    if (tid < 128) {
        q_sh[tid] = query[q * 128 + tid];
        bias_sh[0][tid] = bk0[tid];
        bias_sh[1][tid] = bk1[tid];
        bias_sh[2][tid] = bk2[tid];
    }
    if (tid < 192) off_sh[tid] = offv[q * 192 + tid];
    if (tid < 6) ref_sh[tid] = ref[q * 6 + tid];
    __syncthreads();

    int grp = tid >> 4;  // sample group 0..15
    int d = tid & 15;    // head-dim lane
    #pragma unroll
    for (int it = 0; it < 6; ++it) {
        int s = it * 16 + grp;        // s == (h*3+l)*4+p
        int h = s / 12;
        int lp = s - h * 12;
        int l = lp >> 2;
        const __hip_bfloat16* P; int W, H;
        if (l == 0)      { P = P0; W = 128; H = 128; }
        else if (l == 1) { P = P1; W = 64;  H = 64;  }
        else             { P = P2; W = 32;  H = 32;  }
        float ox = off_sh[2 * s];
        float oy = off_sh[2 * s + 1];
        float rx = ref_sh[2 * l];
        float ry = ref_sh[2 * l + 1];
        float x = fmaf(rx, (float)W, ox) - 0.5f;
        float y = fmaf(ry, (float)H, oy) - 0.5f;
        float x0f = floorf(x), y0f = floorf(y);
        float wx = x - x0f, wy = y - y0f;
        int x0 = (int)x0f, y0 = (int)y0f;
        int x1 = x0 + 1, y1 = y0 + 1;
        float mx0 = (x0 >= 0 && x0 < W) ? 1.f : 0.f;
        float mx1 = (x1 >= 0 && x1 < W) ? 1.f : 0.f;
        float my0 = (y0 >= 0 && y0 < H) ? 1.f : 0.f;
        float my1 = (y1 >= 0 && y1 < H) ? 1.f : 0.f;
        int xc0 = min(max(x0, 0), W - 1), xc1 = min(max(x1, 0), W - 1);
        int yc0 = min(max(y0, 0), H - 1), yc1 = min(max(y1, 0), H - 1);
        int co = h * 16 + d;
        const __hip_bfloat16* base = P + co;
        float v00 = __bfloat162float(base[(size_t)(yc0 * W + xc0) * 128]);
        float v10 = __bfloat162float(base[(size_t)(yc0 * W + xc1) * 128]);
        float v01 = __bfloat162float(base[(size_t)(yc1 * W + xc0) * 128]);
        float v11 = __bfloat162float(base[(size_t)(yc1 * W + xc1) * 128]);
        float w00 = (1.f - wx) * (1.f - wy) * mx0 * my0;
        float w10 = wx * (1.f - wy) * mx1 * my0;
        float w01 = (1.f - wx) * wy * mx0 * my1;
        float w11 = wx * wy * mx1 * my1;
        float kv = fmaf(w00, v00, fmaf(w10, v10, fmaf(w01, v01, w11 * v11))) + bias_sh[l][co];
        float prod = q_sh[co] * kv;
        prod += __shfl_xor(prod, 1);
        prod += __shfl_xor(prod, 2);
        prod += __shfl_xor(prod, 4);
        prod += __shfl_xor(prod, 8);
        k_sh[h][lp][d] = kv;
        if (d == 0) logit_sh[h][lp] = prod;
    }
    __syncthreads();

    if (tid < 128) {
        int h = tid >> 4, dd = tid & 15;
        float m = -1e30f;
        #pragma unroll
        for (int j = 0; j < 12; ++j) m = fmaxf(m, logit_sh[h][j]);
        float ssum = 0.f, o = 0.f;
        #pragma unroll
        for (int j = 0; j < 12; ++j) {
            float e = __expf(0.25f * (logit_sh[h][j] - m));
            ssum += e;
            o = fmaf(e, k_sh[h][j][dd], o);
        }
        hout[q * 128 + tid] = o / ssum;
    }
}

// ---------------------------------------------------------------------------
// Kernel 4: output projection. Tile 64 rows (half) x 64 queries, K=128.
// ---------------------------------------------------------------------------
__global__ __launch_bounds__(256) void outp2_kernel(
    const float* __restrict__ hin, const float* __restrict__ W_out,
    const float* __restrict__ b_out, float* __restrict__ out)
{
    __shared__ float w_sh[64 * 128];  // 32 KB swizzled
    __shared__ float q_sh[64 * 128];  // 32 KB
    int b = blockIdx.x;
    int qblk = b >> 1;
    int half = b & 1;
    int rbase = half * 64;
    int q0 = qblk * 64;
    int tid = threadIdx.x;

    for (int idx = tid; idx < 64 * 32; idx += 256) {
        int rl = idx >> 5;
        int ci4 = idx & 31;
        float4 v = *reinterpret_cast<const float4*>(&W_out[(rbase + rl) * 128 + ci4 * 4]);
        *reinterpret_cast<float4*>(&w_sh[rl * 128 + ((ci4 ^ (rl & 31)) << 2)]) = v;
    }
    for (int idx = tid; idx < 64 * 32; idx += 256) {
        int qq = idx >> 5;
        int ci4 = idx & 31;
        *reinterpret_cast<float4*>(&q_sh[qq * 128 + ci4 * 4]) =
            *reinterpret_cast<const float4*>(&hin[(q0 + qq) * 128 + ci4 * 4]);
    }
    __syncthreads();

    int c0 = tid & 31;   // rows c0, c0+32
    int qg = tid >> 5;   // 8 groups x 8 queries
    float acc[2][8];
    #pragma unroll
    for (int k = 0; k < 2; ++k)
        #pragma unroll
        for (int j = 0; j < 8; ++j) acc[k][j] = 0.f;

    #pragma unroll 4
    for (int ci4 = 0; ci4 < 32; ++ci4) {
        float4 A0 = *reinterpret_cast<const float4*>(&w_sh[c0 * 128 + ((ci4 ^ c0) << 2)]);
        float4 A1 = *reinterpret_cast<const float4*>(&w_sh[(c0 + 32) * 128 + ((ci4 ^ c0) << 2)]);
        #pragma unroll
        for (int j = 0; j < 8; ++j) {
            float4 B = *reinterpret_cast<const float4*>(&q_sh[(qg * 8 + j) * 128 + ci4 * 4]);
            acc[0][j] = fmaf(A0.x, B.x, acc[0][j]);
            acc[0][j] = fmaf(A0.y, B.y, acc[0][j]);
            acc[0][j] = fmaf(A0.z, B.z, acc[0][j]);
            acc[0][j] = fmaf(A0.w, B.w, acc[0][j]);
            acc[1][j] = fmaf(A1.x, B.x, acc[1][j]);
            acc[1][j] = fmaf(A1.y, B.y, acc[1][j]);
            acc[1][j] = fmaf(A1.z, B.z, acc[1][j]);
            acc[1][j] = fmaf(A1.w, B.w, acc[1][j]);
        }
    }
    #pragma unroll
    for (int k = 0; k < 2; ++k) {
        int r = rbase + c0 + 32 * k;
        float bias = b_out[r];
        #pragma unroll
        for (int j = 0; j < 8; ++j)
            out[(q0 + qg * 8 + j) * 128 + r] = acc[k][j] + bias;
    }
}

// ---------------------------------------------------------------------------
extern "C" void kernel_launch(void* const* d_in, const int* in_sizes, int n_in,
                              void* d_out, int out_size, void* d_ws, size_t ws_size,
                              hipStream_t stream) {
    const float* query = (const float*)d_in[0];
    const float* ref   = (const float*)d_in[1];
    const float* feat0 = (const float*)d_in[2];
    const float* feat1 = (const float*)d_in[3];
    const float* feat2 = (const float*)d_in[4];
    const float* W_off = (const float*)d_in[6];
    const float* b_off = (const float*)d_in[7];
    const float* Wk0   = (const float*)d_in[8];
    const float* bk0   = (const float*)d_in[9];
    const float* Wk1   = (const float*)d_in[10];
    const float* bk1   = (const float*)d_in[11];
    const float* Wk2   = (const float*)d_in[12];
    const float* bk2   = (const float*)d_in[13];
    const float* W_out = (const float*)d_in[14];
    const float* b_out = (const float*)d_in[15];
    float* out = (float*)d_out;

    __hip_bfloat16* P0 = (__hip_bfloat16*)d_ws;     // 16384*128 bf16
    __hip_bfloat16* P1 = P0 + 16384 * 128;          // 4096*128
    __hip_bfloat16* P2 = P1 + 4096 * 128;           // 1024*128
    float* offv = (float*)(P2 + 1024 * 128);        // 6400*192 f32 (16B-aligned)
    float* hout = offv + 6400 * 192;                // 6400*128 f32

    hipLaunchKernelGGL((proj2_kernel<128>), dim3(640), dim3(256), 0, stream,
                       feat0, feat1, Wk0, Wk1, P0, P1, 512, 16384, 4096);
    hipLaunchKernelGGL((proj2_kernel<64>), dim3(32), dim3(256), 0, stream,
                       feat2, feat2, Wk2, Wk2, P2, P2, 32, 1024, 1024);
    hipLaunchKernelGGL(off2_kernel, dim3(400), dim3(256), 0, stream,
                       query, W_off, b_off, offv);
    hipLaunchKernelGGL(attn2_kernel, dim3(6400), dim3(256), 0, stream,
                       query, ref, offv, P0, P1, P2, bk0, bk1, bk2, hout);
    hipLaunchKernelGGL(outp2_kernel, dim3(200), dim3(256), 0, stream,
                       hout, W_out, b_out, out);
}

// Round 5
// 157.928 us; speedup vs baseline: 1.2051x; 1.0220x over previous
//
#include <hip/hip_runtime.h>
#include <hip/hip_bf16.h>
#include <math.h>

#define LQ 6400

// ===========================================================================
// Fused prep kernel: blocks [0,640) proj C=128 (feat0:512, feat1:128),
// [640,672) proj C=64 (feat2), [672,1072) offsets GEMM.
// All paths use exactly 64 KB of the shared smem array.
// ===========================================================================

template<int C>
__device__ __forceinline__ void proj_body(
    float* __restrict__ smem,
    const float* __restrict__ feat, const float* __restrict__ Wk,
    __hip_bfloat16* __restrict__ P, int HW, int local)
{
    constexpr int CI4 = C / 4;
    float* wk_sh = smem;            // 64*C floats, float4-granule XOR swizzle
    float* f_sh  = smem + 64 * C;   // C*64 floats
    int pblk = local >> 1;
    int half = local & 1;
    int cbase = half * 64;
    int p0 = pblk * 64;
    int tid = threadIdx.x;

    for (int idx = tid; idx < 64 * CI4; idx += 256) {
        int rl = idx / CI4;
        int ci4 = idx % CI4;
        float4 v = *reinterpret_cast<const float4*>(&Wk[(cbase + rl) * C + ci4 * 4]);
        *reinterpret_cast<float4*>(&wk_sh[rl * C + ((ci4 ^ (rl & (CI4 - 1))) << 2)]) = v;
    }
    for (int idx = tid; idx < C * 16; idx += 256) {
        int ci = idx >> 4;
        int pp4 = idx & 15;
        float4 v = *reinterpret_cast<const float4*>(&feat[ci * HW + p0 + pp4 * 4]);
        *reinterpret_cast<float4*>(&f_sh[ci * 64 + pp4 * 4]) = v;
    }
    __syncthreads();

    int c0 = tid & 31;
    int pg = tid >> 5;
    const int sw = c0 & (CI4 - 1);
    float acc[2][8];
    #pragma unroll
    for (int k = 0; k < 2; ++k)
        #pragma unroll
        for (int j = 0; j < 8; ++j) acc[k][j] = 0.f;

    #pragma unroll 4
    for (int ci4 = 0; ci4 < CI4; ++ci4) {
        float4 A0 = *reinterpret_cast<const float4*>(&wk_sh[c0 * C + ((ci4 ^ sw) << 2)]);
        float4 A1 = *reinterpret_cast<const float4*>(&wk_sh[(c0 + 32) * C + ((ci4 ^ sw) << 2)]);
        float a0v[4] = {A0.x, A0.y, A0.z, A0.w};
        float a1v[4] = {A1.x, A1.y, A1.z, A1.w};
        #pragma unroll
        for (int jj = 0; jj < 4; ++jj) {
            int ci = ci4 * 4 + jj;
            float4 Blo = *reinterpret_cast<const float4*>(&f_sh[ci * 64 + pg * 8]);
            float4 Bhi = *reinterpret_cast<const float4*>(&f_sh[ci * 64 + pg * 8 + 4]);
            float bv[8] = {Blo.x, Blo.y, Blo.z, Blo.w, Bhi.x, Bhi.y, Bhi.z, Bhi.w};
            #pragma unroll
            for (int j = 0; j < 8; ++j) {
                acc[0][j] = fmaf(a0v[jj], bv[j], acc[0][j]);
                acc[1][j] = fmaf(a1v[jj], bv[j], acc[1][j]);
            }
        }
    }
    #pragma unroll
    for (int k = 0; k < 2; ++k) {
        int co = cbase + c0 + 32 * k;
        #pragma unroll
        for (int j = 0; j < 8; ++j)
            P[(size_t)(p0 + pg * 8 + j) * 128 + co] = __float2bfloat16(acc[k][j]);
    }
}

__device__ __forceinline__ void off_body(
    float* __restrict__ smem,
    const float* __restrict__ query, const float* __restrict__ W_off,
    const float* __restrict__ b_off, float* __restrict__ offv, int local)
{
    float* w_sh = smem;            // 96*128
    float* q_sh = smem + 96 * 128; // 32*128
    int qblk = local >> 1;
    int half = local & 1;
    int rbase = half * 96;
    int q0 = qblk * 32;
    int tid = threadIdx.x;

    for (int idx = tid; idx < 96 * 32; idx += 256) {
        int rl = idx >> 5;
        int ci4 = idx & 31;
        float4 v = *reinterpret_cast<const float4*>(&W_off[(rbase + rl) * 128 + ci4 * 4]);
        *reinterpret_cast<float4*>(&w_sh[rl * 128 + ((ci4 ^ (rl & 31)) << 2)]) = v;
    }
    for (int idx = tid; idx < 32 * 32; idx += 256) {
        int qq = idx >> 5;
        int ci4 = idx & 31;
        *reinterpret_cast<float4*>(&q_sh[qq * 128 + ci4 * 4]) =
            *reinterpret_cast<const float4*>(&query[(q0 + qq) * 128 + ci4 * 4]);
    }
    __syncthreads();

    int c0 = tid & 31;
    int qg = tid >> 5;
    float acc[3][4];
    #pragma unroll
    for (int k = 0; k < 3; ++k)
        #pragma unroll
        for (int j = 0; j < 4; ++j) acc[k][j] = 0.f;

    #pragma unroll 4
    for (int ci4 = 0; ci4 < 32; ++ci4) {
        float4 A[3];
        #pragma unroll
        for (int k = 0; k < 3; ++k)
            A[k] = *reinterpret_cast<const float4*>(&w_sh[(c0 + 32 * k) * 128 + ((ci4 ^ c0) << 2)]);
        #pragma unroll
        for (int j = 0; j < 4; ++j) {
            float4 B = *reinterpret_cast<const float4*>(&q_sh[(qg * 4 + j) * 128 + ci4 * 4]);
            #pragma unroll
            for (int k = 0; k < 3; ++k) {
                acc[k][j] = fmaf(A[k].x, B.x, acc[k][j]);
                acc[k][j] = fmaf(A[k].y, B.y, acc[k][j]);
                acc[k][j] = fmaf(A[k].z, B.z, acc[k][j]);
                acc[k][j] = fmaf(A[k].w, B.w, acc[k][j]);
            }
        }
    }
    #pragma unroll
    for (int k = 0; k < 3; ++k) {
        int r = rbase + c0 + 32 * k;
        float bias = b_off[r];
        #pragma unroll
        for (int j = 0; j < 4; ++j)
            offv[(q0 + qg * 4 + j) * 192 + r] = acc[k][j] + bias;
    }
}

__global__ __launch_bounds__(256) void prep_kernel(
    const float* __restrict__ feat0, const float* __restrict__ feat1,
    const float* __restrict__ feat2,
    const float* __restrict__ Wk0, const float* __restrict__ Wk1,
    const float* __restrict__ Wk2,
    __hip_bfloat16* __restrict__ P0, __hip_bfloat16* __restrict__ P1,
    __hip_bfloat16* __restrict__ P2,
    const float* __restrict__ query, const float* __restrict__ W_off,
    const float* __restrict__ b_off, float* __restrict__ offv)
{
    __shared__ __align__(16) float smem[16384];  // 64 KB
    int b = blockIdx.x;
    if (b < 512) {
        proj_body<128>(smem, feat0, Wk0, P0, 16384, b);
    } else if (b < 640) {
        proj_body<128>(smem, feat1, Wk1, P1, 4096, b - 512);
    } else if (b < 672) {
        proj_body<64>(smem, feat2, Wk2, P2, 1024, b - 640);
    } else {
        off_body(smem, query, W_off, b_off, offv, b - 672);
    }
}

// ===========================================================================
// attn3: one 128-thread block per query. 16 lanes per sample:
// lane = (corner c=d>>2, channel-quad=d&3); one uint2 (4 bf16) load per lane,
// all 12 sample loads batched; corner-reduce via shfl_xor(4,8), logit via
// shfl_xor(1,2). Phase 2: softmax + combine, all 128 threads.
// ===========================================================================
__global__ __launch_bounds__(128) void attn3_kernel(
    const float* __restrict__ query, const float* __restrict__ ref,
    const float* __restrict__ offv,
    const __hip_bfloat16* __restrict__ P0, const __hip_bfloat16* __restrict__ P1,
    const __hip_bfloat16* __restrict__ P2,
    const float* __restrict__ bk0, const float* __restrict__ bk1,
    const float* __restrict__ bk2,
    float* __restrict__ hout)
{
    __shared__ float q_sh[128];
    __shared__ float off_sh[192];
    __shared__ float ref_sh[6];
    __shared__ float bias_sh[3][128];
    __shared__ float logit_sh[96];
    __shared__ __align__(16) float k_sh[8 * 196];  // stride 196 breaks phase-2 conflicts
    int q = blockIdx.x;
    int tid = threadIdx.x;
    q_sh[tid] = query[q * 128 + tid];
    bias_sh[0][tid] = bk0[tid];
    bias_sh[1][tid] = bk1[tid];
    bias_sh[2][tid] = bk2[tid];
    off_sh[tid] = offv[q * 192 + tid];
    if (tid < 64) off_sh[128 + tid] = offv[q * 192 + 128 + tid];
    if (tid < 6) ref_sh[tid] = ref[q * 6 + tid];
    __syncthreads();

    const int grp = tid >> 4;   // 0..7
    const int d = tid & 15;
    const int c = d >> 2;       // corner
    const int quad = d & 3;     // channel quad
    const int dxl = c & 1;
    const int dyl = c >> 1;

    uint2 raw[12];
    float wcv[12];
    // ---- issue all 12 gathers back-to-back ----
    #pragma unroll
    for (int it = 0; it < 12; ++it) {
        int s = it * 8 + grp;            // (h*3+l)*4+p
        int h = (s * 171) >> 11;         // s/12 for s<96
        int lp = s - h * 12;
        int l = lp >> 2;
        int W = 128 >> l;                // square levels: H == W
        float ox = off_sh[2 * s];
        float oy = off_sh[2 * s + 1];
        float x = fmaf(ref_sh[2 * l], (float)W, ox) - 0.5f;
        float y = fmaf(ref_sh[2 * l + 1], (float)W, oy) - 0.5f;
        float x0f = floorf(x), y0f = floorf(y);
        float wx = x - x0f, wy = y - y0f;
        int xs = (int)x0f + dxl;
        int ys = (int)y0f + dyl;
        float m = (xs >= 0 && xs < W && ys >= 0 && ys < W) ? 1.f : 0.f;
        float fx = dxl ? wx : 1.f - wx;
        float fy = dyl ? wy : 1.f - wy;
        wcv[it] = fx * fy * m;
        int xc = min(max(xs, 0), W - 1);
        int yc = min(max(ys, 0), W - 1);
        const __hip_bfloat16* P = (l == 0) ? P0 : ((l == 1) ? P1 : P2);
        size_t idx = (size_t)(yc * W + xc) * 128 + h * 16 + quad * 4;
        raw[it] = *reinterpret_cast<const uint2*>(P + idx);
    }

    // ---- process ----
    #pragma unroll
    for (int it = 0; it < 12; ++it) {
        int s = it * 8 + grp;
        int h = (s * 171) >> 11;
        int lp = s - h * 12;
        int l = lp >> 2;
        unsigned a = raw[it].x, bb = raw[it].y;
        float w = wcv[it];
        float k0 = w * __uint_as_float(a << 16);
        float k1 = w * __uint_as_float(a & 0xffff0000u);
        float k2 = w * __uint_as_float(bb << 16);
        float k3 = w * __uint_as_float(bb & 0xffff0000u);
        k0 += __shfl_xor(k0, 4); k1 += __shfl_xor(k1, 4);
        k2 += __shfl_xor(k2, 4); k3 += __shfl_xor(k3, 4);
        k0 += __shfl_xor(k0, 8); k1 += __shfl_xor(k1, 8);
        k2 += __shfl_xor(k2, 8); k3 += __shfl_xor(k3, 8);
        int co4 = h * 16 + quad * 4;
        k0 += bias_sh[l][co4 + 0];
        k1 += bias_sh[l][co4 + 1];
        k2 += bias_sh[l][co4 + 2];
        k3 += bias_sh[l][co4 + 3];
        float lg = q_sh[co4] * k0;
        lg = fmaf(q_sh[co4 + 1], k1, lg);
        lg = fmaf(q_sh[co4 + 2], k2, lg);
        lg = fmaf(q_sh[co4 + 3], k3, lg);
        lg += __shfl_xor(lg, 1);
        lg += __shfl_xor(lg, 2);
        if (d < 4) {   // d == quad here; corner 0 lanes hold the full sums
            float4 kv = make_float4(k0, k1, k2, k3);
            *reinterpret_cast<float4*>(&k_sh[h * 196 + lp * 16 + d * 4]) = kv;
        }
        if (d == 0) logit_sh[h * 12 + lp] = lg;
    }
    __syncthreads();

    // ---- softmax + combine ----
    int h2 = tid >> 4, dd = tid & 15;
    float m = -1e30f;
    #pragma unroll
    for (int j = 0; j < 12; ++j) m = fmaxf(m, logit_sh[h2 * 12 + j]);
    float ssum = 0.f, o = 0.f;
    #pragma unroll
    for (int j = 0; j < 12; ++j) {
        float e = __expf(0.25f * (logit_sh[h2 * 12 + j] - m));
        ssum += e;
        o = fmaf(e, k_sh[h2 * 196 + j * 16 + dd], o);
    }
    hout[q * 128 + tid] = o / ssum;
}

// ===========================================================================
// Kernel 4: output projection. Tile 64 rows (half) x 64 queries, K=128.
// ===========================================================================
__global__ __launch_bounds__(256) void outp2_kernel(
    const float* __restrict__ hin, const float* __restrict__ W_out,
    const float* __restrict__ b_out, float* __restrict__ out)
{
    __shared__ __align__(16) float w_sh[64 * 128];
    __shared__ __align__(16) float q_sh[64 * 128];
    int b = blockIdx.x;
    int qblk = b >> 1;
    int half = b & 1;
    int rbase = half * 64;
    int q0 = qblk * 64;
    int tid = threadIdx.x;

    for (int idx = tid; idx < 64 * 32; idx += 256) {
        int rl = idx >> 5;
        int ci4 = idx & 31;
        float4 v = *reinterpret_cast<const float4*>(&W_out[(rbase + rl) * 128 + ci4 * 4]);
        *reinterpret_cast<float4*>(&w_sh[rl * 128 + ((ci4 ^ (rl & 31)) << 2)]) = v;
    }
    for (int idx = tid; idx < 64 * 32; idx += 256) {
        int qq = idx >> 5;
        int ci4 = idx & 31;
        *reinterpret_cast<float4*>(&q_sh[qq * 128 + ci4 * 4]) =
            *reinterpret_cast<const float4*>(&hin[(q0 + qq) * 128 + ci4 * 4]);
    }
    __syncthreads();

    int c0 = tid & 31;
    int qg = tid >> 5;
    float acc[2][8];
    #pragma unroll
    for (int k = 0; k < 2; ++k)
        #pragma unroll
        for (int j = 0; j < 8; ++j) acc[k][j] = 0.f;

    #pragma unroll 4
    for (int ci4 = 0; ci4 < 32; ++ci4) {
        float4 A0 = *reinterpret_cast<const float4*>(&w_sh[c0 * 128 + ((ci4 ^ c0) << 2)]);
        float4 A1 = *reinterpret_cast<const float4*>(&w_sh[(c0 + 32) * 128 + ((ci4 ^ c0) << 2)]);
        #pragma unroll
        for (int j = 0; j < 8; ++j) {
            float4 B = *reinterpret_cast<const float4*>(&q_sh[(qg * 8 + j) * 128 + ci4 * 4]);
            acc[0][j] = fmaf(A0.x, B.x, acc[0][j]);
            acc[0][j] = fmaf(A0.y, B.y, acc[0][j]);
            acc[0][j] = fmaf(A0.z, B.z, acc[0][j]);
            acc[0][j] = fmaf(A0.w, B.w, acc[0][j]);
            acc[1][j] = fmaf(A1.x, B.x, acc[1][j]);
            acc[1][j] = fmaf(A1.y, B.y, acc[1][j]);
            acc[1][j] = fmaf(A1.z, B.z, acc[1][j]);
            acc[1][j] = fmaf(A1.w, B.w, acc[1][j]);
        }
    }
    #pragma unroll
    for (int k = 0; k < 2; ++k) {
        int r = rbase + c0 + 32 * k;
        float bias = b_out[r];
        #pragma unroll
        for (int j = 0; j < 8; ++j)
            out[(q0 + qg * 8 + j) * 128 + r] = acc[k][j] + bias;
    }
}

// ===========================================================================
extern "C" void kernel_launch(void* const* d_in, const int* in_sizes, int n_in,
                              void* d_out, int out_size, void* d_ws, size_t ws_size,
                              hipStream_t stream) {
    const float* query = (const float*)d_in[0];
    const float* ref   = (const float*)d_in[1];
    const float* feat0 = (const float*)d_in[2];
    const float* feat1 = (const float*)d_in[3];
    const float* feat2 = (const float*)d_in[4];
    const float* W_off = (const float*)d_in[6];
    const float* b_off = (const float*)d_in[7];
    const float* Wk0   = (const float*)d_in[8];
    const float* bk0   = (const float*)d_in[9];
    const float* Wk1   = (const float*)d_in[10];
    const float* bk1   = (const float*)d_in[11];
    const float* Wk2   = (const float*)d_in[12];
    const float* bk2   = (const float*)d_in[13];
    const float* W_out = (const float*)d_in[14];
    const float* b_out = (const float*)d_in[15];
    float* out = (float*)d_out;

    __hip_bfloat16* P0 = (__hip_bfloat16*)d_ws;     // 16384*128 bf16
    __hip_bfloat16* P1 = P0 + 16384 * 128;          // 4096*128
    __hip_bfloat16* P2 = P1 + 4096 * 128;           // 1024*128
    float* offv = (float*)(P2 + 1024 * 128);        // 6400*192 f32
    float* hout = offv + 6400 * 192;                // 6400*128 f32

    hipLaunchKernelGGL(prep_kernel, dim3(1072), dim3(256), 0, stream,
                       feat0, feat1, feat2, Wk0, Wk1, Wk2, P0, P1, P2,
                       query, W_off, b_off, offv);
    hipLaunchKernelGGL(attn3_kernel, dim3(6400), dim3(128), 0, stream,
                       query, ref, offv, P0, P1, P2, bk0, bk1, bk2, hout);
    hipLaunchKernelGGL(outp2_kernel, dim3(200), dim3(256), 0, stream,
                       hout, W_out, b_out, out);
}

// Round 6
// 133.478 us; speedup vs baseline: 1.4258x; 1.1832x over previous
//
#include <hip/hip_runtime.h>
#include <hip/hip_bf16.h>
#include <math.h>

typedef __attribute__((ext_vector_type(8))) short bf16x8;
typedef __attribute__((ext_vector_type(4))) float f32x4;

__device__ __forceinline__ unsigned f2bfu(float f) {
    __hip_bfloat16 b = __float2bfloat16(f);
    return (unsigned)*reinterpret_cast<unsigned short*>(&b);
}

__device__ __forceinline__ bf16x8 cvt8(float4 a, float4 b) {
    bf16x8 r;
    r[0] = (short)f2bfu(a.x); r[1] = (short)f2bfu(a.y);
    r[2] = (short)f2bfu(a.z); r[3] = (short)f2bfu(a.w);
    r[4] = (short)f2bfu(b.x); r[5] = (short)f2bfu(b.y);
    r[6] = (short)f2bfu(b.z); r[7] = (short)f2bfu(b.w);
    return r;
}

// ===========================================================================
// prep kernel: blocks [0,128) L0 proj, [128,160) L1 proj, [160,168) L2 proj,
// [168,268) offsets GEMM. MFMA bf16 throughout.
// proj: P[h][pix][16] = Wk_head_h(16xC) @ feat(Cx128pix), per-head layout.
// ===========================================================================
template<int C>
__device__ __forceinline__ void proj_mfma(
    unsigned short* lds, const float* __restrict__ feat,
    const float* __restrict__ Wk, __hip_bfloat16* __restrict__ P,
    int HW, int pblk)
{
    constexpr int GR = C / 8;    // 16B granules per pixel row
    constexpr int KK = C / 32;   // mfma chain length over K
    const int tid = threadIdx.x;
    const int p0 = pblk * 128;

    // stage feat tile -> bf16 LDS [pix][C], granule-XOR swizzle (by pix)
    for (int u = tid; u < (C / 2) * 32; u += 256) {
        int cip = u >> 5;
        int p4 = (u & 31) << 2;
        int ci = cip << 1;
        float4 lo = *reinterpret_cast<const float4*>(feat + (size_t)ci * HW + p0 + p4);
        float4 hi = *reinterpret_cast<const float4*>(feat + (size_t)(ci + 1) * HW + p0 + p4);
        float lov[4] = {lo.x, lo.y, lo.z, lo.w};
        float hiv[4] = {hi.x, hi.y, hi.z, hi.w};
        int g = ci >> 3;
        #pragma unroll
        for (int j = 0; j < 4; ++j) {
            int pix = p4 + j;
            int gs = g ^ (pix & (GR - 1));
            unsigned pack = f2bfu(lov[j]) | (f2bfu(hiv[j]) << 16);
            *reinterpret_cast<unsigned*>(lds + pix * C + gs * 8 + (ci & 7)) = pack;
        }
    }
    __syncthreads();

    const int wave = tid >> 6, lane = tid & 63;
    const int col = lane & 15, g4 = lane >> 4;

    // B fragments: feat[k][pix], lane: n=col(pix), k window = kk*32+g4*8
    bf16x8 bfrag[2][KK];
    #pragma unroll
    for (int st = 0; st < 2; ++st) {
        int pix = (wave * 2 + st) * 16 + col;
        #pragma unroll
        for (int kk = 0; kk < KK; ++kk) {
            int gs = (kk * 4 + g4) ^ (pix & (GR - 1));
            bfrag[st][kk] = *reinterpret_cast<const bf16x8*>(lds + pix * C + gs * 8);
        }
    }
    #pragma unroll
    for (int h = 0; h < 8; ++h) {
        // A fragments: Wk rows (16 per head), from global + cvt (L1/L2-hot)
        bf16x8 afrag[KK];
        #pragma unroll
        for (int kk = 0; kk < KK; ++kk) {
            const float* wp = Wk + (size_t)(h * 16 + col) * C + kk * 32 + g4 * 8;
            afrag[kk] = cvt8(*reinterpret_cast<const float4*>(wp),
                             *reinterpret_cast<const float4*>(wp + 4));
        }
        #pragma unroll
        for (int st = 0; st < 2; ++st) {
            f32x4 acc = {0.f, 0.f, 0.f, 0.f};
            #pragma unroll
            for (int kk = 0; kk < KK; ++kk)
                acc = __builtin_amdgcn_mfma_f32_16x16x32_bf16(afrag[kk], bfrag[st][kk], acc, 0, 0, 0);
            // D: col=pix, rows g4*4..+3 = channel d; write 4 bf16 (8B)
            int pix = p0 + (wave * 2 + st) * 16 + col;
            unsigned lo = f2bfu(acc[0]) | (f2bfu(acc[1]) << 16);
            unsigned hi = f2bfu(acc[2]) | (f2bfu(acc[3]) << 16);
            uint2 od = make_uint2(lo, hi);
            *reinterpret_cast<uint2*>(reinterpret_cast<char*>(P) +
                (size_t)(h * HW + pix) * 32 + g4 * 8) = od;
        }
    }
}

__device__ __forceinline__ void off_mfma(
    const float* __restrict__ query, const float* __restrict__ W_off,
    const float* __restrict__ b_off, float* __restrict__ offv, int qblk)
{
    const int tid = threadIdx.x;
    const int wave = tid >> 6, lane = tid & 63;
    const int col = lane & 15, g4 = lane >> 4;
    const int q = qblk * 64 + wave * 16 + col;

    // B fragments: query^T[k][q] = query[q][k], straight from global
    bf16x8 bfrag[4];
    #pragma unroll
    for (int kk = 0; kk < 4; ++kk) {
        const float* qp = query + (size_t)q * 128 + kk * 32 + g4 * 8;
        bfrag[kk] = cvt8(*reinterpret_cast<const float4*>(qp),
                         *reinterpret_cast<const float4*>(qp + 4));
    }
    #pragma unroll
    for (int mt = 0; mt < 12; ++mt) {
        bf16x8 afrag[4];
        #pragma unroll
        for (int kk = 0; kk < 4; ++kk) {
            const float* wp = W_off + (size_t)(mt * 16 + col) * 128 + kk * 32 + g4 * 8;
            afrag[kk] = cvt8(*reinterpret_cast<const float4*>(wp),
                             *reinterpret_cast<const float4*>(wp + 4));
        }
        f32x4 acc = {0.f, 0.f, 0.f, 0.f};
        #pragma unroll
        for (int kk = 0; kk < 4; ++kk)
            acc = __builtin_amdgcn_mfma_f32_16x16x32_bf16(afrag[kk], bfrag[kk], acc, 0, 0, 0);
        float4 bias = *reinterpret_cast<const float4*>(b_off + mt * 16 + g4 * 4);
        float4 o = make_float4(acc[0] + bias.x, acc[1] + bias.y,
                               acc[2] + bias.z, acc[3] + bias.w);
        *reinterpret_cast<float4*>(offv + (size_t)q * 192 + mt * 16 + g4 * 4) = o;
    }
}

__global__ __launch_bounds__(256) void prep3_kernel(
    const float* __restrict__ feat0, const float* __restrict__ feat1,
    const float* __restrict__ feat2,
    const float* __restrict__ Wk0, const float* __restrict__ Wk1,
    const float* __restrict__ Wk2,
    __hip_bfloat16* __restrict__ P0, __hip_bfloat16* __restrict__ P1,
    __hip_bfloat16* __restrict__ P2,
    const float* __restrict__ query, const float* __restrict__ W_off,
    const float* __restrict__ b_off, float* __restrict__ offv)
{
    __shared__ __align__(16) unsigned short lds[128 * 128];  // 32 KB
    int b = blockIdx.x;
    if (b < 128)      proj_mfma<128>(lds, feat0, Wk0, P0, 16384, b);
    else if (b < 160) proj_mfma<128>(lds, feat1, Wk1, P1, 4096, b - 128);
    else if (b < 168) proj_mfma<64>(lds, feat2, Wk2, P2, 1024, b - 160);
    else              off_mfma(query, W_off, b_off, offv, b - 168);
}

// ===========================================================================
// attn4: one 128-thread block per query. Geometry precomputed per sample
// (96 threads), then 4 lanes per sample gather: lane=(quad), 4 corner uint2
// loads each, bilinear in-register, logit reduce via shfl_xor(1,2).
// P layout: per-head [h][pix][16ch] bf16 (32 B/pixel).
// ===========================================================================
__global__ __launch_bounds__(128) void attn4_kernel(
    const float* __restrict__ query, const float* __restrict__ ref,
    const float* __restrict__ offv,
    const __hip_bfloat16* __restrict__ P0, const __hip_bfloat16* __restrict__ P1,
    const __hip_bfloat16* __restrict__ P2,
    const float* __restrict__ bk0, const float* __restrict__ bk1,
    const float* __restrict__ bk2,
    float* __restrict__ hout)
{
    __shared__ __align__(16) float q_sh[128];
    __shared__ __align__(16) float bias_sh[3][128];
    __shared__ float logit_sh[96];
    __shared__ __align__(16) float k_sh[96 * 20];     // stride 20: conflict-safe
    __shared__ __align__(16) unsigned gaddr[96][4];   // byte offsets per corner
    __shared__ __align__(16) float gw[96][4];
    int q = blockIdx.x;
    int tid = threadIdx.x;
    q_sh[tid] = query[q * 128 + tid];
    bias_sh[0][tid] = bk0[tid];
    bias_sh[1][tid] = bk1[tid];
    bias_sh[2][tid] = bk2[tid];
    if (tid < 96) {
        int s = tid;
        int h = (s * 171) >> 11;       // s/12
        int lp = s - h * 12;
        int l = lp >> 2;
        int W = 128 >> l;
        float ox = offv[q * 192 + 2 * s];
        float oy = offv[q * 192 + 2 * s + 1];
        float x = fmaf(ref[q * 6 + 2 * l], (float)W, ox) - 0.5f;
        float y = fmaf(ref[q * 6 + 2 * l + 1], (float)W, oy) - 0.5f;
        float x0f = floorf(x), y0f = floorf(y);
        float wx = x - x0f, wy = y - y0f;
        int x0 = (int)x0f, y0 = (int)y0f;
        int x1 = x0 + 1, y1 = y0 + 1;
        float mx0 = (x0 >= 0 && x0 < W) ? 1.f : 0.f;
        float mx1 = (x1 >= 0 && x1 < W) ? 1.f : 0.f;
        float my0 = (y0 >= 0 && y0 < W) ? 1.f : 0.f;
        float my1 = (y1 >= 0 && y1 < W) ? 1.f : 0.f;
        int xc0 = min(max(x0, 0), W - 1), xc1 = min(max(x1, 0), W - 1);
        int yc0 = min(max(y0, 0), W - 1), yc1 = min(max(y1, 0), W - 1);
        unsigned pb = (unsigned)(h * W * W) * 32u;
        gaddr[s][0] = pb + (unsigned)(yc0 * W + xc0) * 32u;
        gaddr[s][1] = pb + (unsigned)(yc0 * W + xc1) * 32u;
        gaddr[s][2] = pb + (unsigned)(yc1 * W + xc0) * 32u;
        gaddr[s][3] = pb + (unsigned)(yc1 * W + xc1) * 32u;
        gw[s][0] = (1.f - wx) * (1.f - wy) * mx0 * my0;
        gw[s][1] = wx * (1.f - wy) * mx1 * my0;
        gw[s][2] = (1.f - wx) * wy * mx0 * my1;
        gw[s][3] = wx * wy * mx1 * my1;
    }
    __syncthreads();

    const int quad = tid & 3;
    uint2 raw[3][4];
    float4 wv[3];
    int hs[3], lps[3], lvs[3];
    #pragma unroll
    for (int it = 0; it < 3; ++it) {
        int s = it * 32 + (tid >> 2);
        int h = (s * 171) >> 11;
        int lp = s - h * 12;
        int l = lp >> 2;
        hs[it] = h; lps[it] = lp; lvs[it] = l;
        uint4 av = *reinterpret_cast<const uint4*>(&gaddr[s][0]);
        wv[it] = *reinterpret_cast<const float4*>(&gw[s][0]);
        const char* base = ((l == 0) ? (const char*)P0 :
                            (l == 1) ? (const char*)P1 : (const char*)P2) + quad * 8;
        raw[it][0] = *reinterpret_cast<const uint2*>(base + av.x);
        raw[it][1] = *reinterpret_cast<const uint2*>(base + av.y);
        raw[it][2] = *reinterpret_cast<const uint2*>(base + av.z);
        raw[it][3] = *reinterpret_cast<const uint2*>(base + av.w);
    }
    #pragma unroll
    for (int it = 0; it < 3; ++it) {
        int s = it * 32 + (tid >> 2);
        int h = hs[it], l = lvs[it];
        float k0 = 0.f, k1 = 0.f, k2 = 0.f, k3 = 0.f;
        float wc[4] = {wv[it].x, wv[it].y, wv[it].z, wv[it].w};
        #pragma unroll
        for (int cnr = 0; cnr < 4; ++cnr) {
            unsigned a = raw[it][cnr].x, b2 = raw[it][cnr].y;
            float w = wc[cnr];
            k0 = fmaf(w, __uint_as_float(a << 16), k0);
            k1 = fmaf(w, __uint_as_float(a & 0xffff0000u), k1);
            k2 = fmaf(w, __uint_as_float(b2 << 16), k2);
            k3 = fmaf(w, __uint_as_float(b2 & 0xffff0000u), k3);
        }
        int co = h * 16 + quad * 4;
        float4 bias = *reinterpret_cast<const float4*>(&bias_sh[l][co]);
        k0 += bias.x; k1 += bias.y; k2 += bias.z; k3 += bias.w;
        float4 qv = *reinterpret_cast<const float4*>(&q_sh[co]);
        float lg = k0 * qv.x;
        lg = fmaf(k1, qv.y, lg);
        lg = fmaf(k2, qv.z, lg);
        lg = fmaf(k3, qv.w, lg);
        lg += __shfl_xor(lg, 1);
        lg += __shfl_xor(lg, 2);
        *reinterpret_cast<float4*>(&k_sh[s * 20 + quad * 4]) = make_float4(k0, k1, k2, k3);
        if (quad == 0) logit_sh[s] = lg;
    }
    __syncthreads();

    // softmax + combine
    int h2 = tid >> 4, dd = tid & 15;
    float m = -1e30f;
    #pragma unroll
    for (int j = 0; j < 12; ++j) m = fmaxf(m, logit_sh[h2 * 12 + j]);
    float ssum = 0.f, o = 0.f;
    #pragma unroll
    for (int j = 0; j < 12; ++j) {
        float e = __expf(0.25f * (logit_sh[h2 * 12 + j] - m));
        ssum += e;
        o = fmaf(e, k_sh[(h2 * 12 + j) * 20 + dd], o);
    }
    hout[q * 128 + tid] = o / ssum;
}

// ===========================================================================
// output projection (unchanged structure). Tile 64 rows x 64 queries, K=128.
// ===========================================================================
__global__ __launch_bounds__(256) void outp2_kernel(
    const float* __restrict__ hin, const float* __restrict__ W_out,
    const float* __restrict__ b_out, float* __restrict__ out)
{
    __shared__ __align__(16) float w_sh[64 * 128];
    __shared__ __align__(16) float q_sh[64 * 128];
    int b = blockIdx.x;
    int qblk = b >> 1;
    int half = b & 1;
    int rbase = half * 64;
    int q0 = qblk * 64;
    int tid = threadIdx.x;

    for (int idx = tid; idx < 64 * 32; idx += 256) {
        int rl = idx >> 5;
        int ci4 = idx & 31;
        float4 v = *reinterpret_cast<const float4*>(&W_out[(rbase + rl) * 128 + ci4 * 4]);
        *reinterpret_cast<float4*>(&w_sh[rl * 128 + ((ci4 ^ (rl & 31)) << 2)]) = v;
    }
    for (int idx = tid; idx < 64 * 32; idx += 256) {
        int qq = idx >> 5;
        int ci4 = idx & 31;
        *reinterpret_cast<float4*>(&q_sh[qq * 128 + ci4 * 4]) =
            *reinterpret_cast<const float4*>(&hin[(q0 + qq) * 128 + ci4 * 4]);
    }
    __syncthreads();

    int c0 = tid & 31;
    int qg = tid >> 5;
    float acc[2][8];
    #pragma unroll
    for (int k = 0; k < 2; ++k)
        #pragma unroll
        for (int j = 0; j < 8; ++j) acc[k][j] = 0.f;

    #pragma unroll 4
    for (int ci4 = 0; ci4 < 32; ++ci4) {
        float4 A0 = *reinterpret_cast<const float4*>(&w_sh[c0 * 128 + ((ci4 ^ c0) << 2)]);
        float4 A1 = *reinterpret_cast<const float4*>(&w_sh[(c0 + 32) * 128 + ((ci4 ^ c0) << 2)]);
        #pragma unroll
        for (int j = 0; j < 8; ++j) {
            float4 B = *reinterpret_cast<const float4*>(&q_sh[(qg * 8 + j) * 128 + ci4 * 4]);
            acc[0][j] = fmaf(A0.x, B.x, acc[0][j]);
            acc[0][j] = fmaf(A0.y, B.y, acc[0][j]);
            acc[0][j] = fmaf(A0.z, B.z, acc[0][j]);
            acc[0][j] = fmaf(A0.w, B.w, acc[0][j]);
            acc[1][j] = fmaf(A1.x, B.x, acc[1][j]);
            acc[1][j] = fmaf(A1.y, B.y, acc[1][j]);
            acc[1][j] = fmaf(A1.z, B.z, acc[1][j]);
            acc[1][j] = fmaf(A1.w, B.w, acc[1][j]);
        }
    }
    #pragma unroll
    for (int k = 0; k < 2; ++k) {
        int r = rbase + c0 + 32 * k;
        float bias = b_out[r];
        #pragma unroll
        for (int j = 0; j < 8; ++j)
            out[(q0 + qg * 8 + j) * 128 + r] = acc[k][j] + bias;
    }
}

// ===========================================================================
extern "C" void kernel_launch(void* const* d_in, const int* in_sizes, int n_in,
                              void* d_out, int out_size, void* d_ws, size_t ws_size,
                              hipStream_t stream) {
    const float* query = (const float*)d_in[0];
    const float* ref   = (const float*)d_in[1];
    const float* feat0 = (const float*)d_in[2];
    const float* feat1 = (const float*)d_in[3];
    const float* feat2 = (const float*)d_in[4];
    const float* W_off = (const float*)d_in[6];
    const float* b_off = (const float*)d_in[7];
    const float* Wk0   = (const float*)d_in[8];
    const float* bk0   = (const float*)d_in[9];
    const float* Wk1   = (const float*)d_in[10];
    const float* bk1   = (const float*)d_in[11];
    const float* Wk2   = (const float*)d_in[12];
    const float* bk2   = (const float*)d_in[13];
    const float* W_out = (const float*)d_in[14];
    const float* b_out = (const float*)d_in[15];
    float* out = (float*)d_out;

    __hip_bfloat16* P0 = (__hip_bfloat16*)d_ws;     // [8][16384][16] bf16
    __hip_bfloat16* P1 = P0 + 8 * 16384 * 16;       // [8][4096][16]
    __hip_bfloat16* P2 = P1 + 8 * 4096 * 16;        // [8][1024][16]
    float* offv = (float*)(P2 + 8 * 1024 * 16);     // [6400][192] f32
    float* hout = offv + 6400 * 192;                // [6400][128] f32

    hipLaunchKernelGGL(prep3_kernel, dim3(268), dim3(256), 0, stream,
                       feat0, feat1, feat2, Wk0, Wk1, Wk2, P0, P1, P2,
                       query, W_off, b_off, offv);
    hipLaunchKernelGGL(attn4_kernel, dim3(6400), dim3(128), 0, stream,
                       query, ref, offv, P0, P1, P2, bk0, bk1, bk2, hout);
    hipLaunchKernelGGL(outp2_kernel, dim3(200), dim3(256), 0, stream,
                       hout, W_out, b_out, out);
}